// Round 4
// baseline (173.663 us; speedup 1.0000x reference)
//
#include <hip/hip_runtime.h>
#include <math.h>
#include <stdint.h>

#define BATCH 4
#define CH    256
#define HH    80
#define WW    80
#define HW    (HH*WW)        // 6400
#define NPIX  (BATCH*HW)     // 25600
#define KK    9
#define CO    18             // 2*K*K offset channels
#define NCHUNK 72            // 9 taps * 8 groups of 32 channels
#define WROW  40             // padded K-stride (elements) for LDS weight tile (80 B)
#define PXB   32             // pixels per block
#define NBLK  (NPIX/PXB)     // 800 blocks

typedef _Float16 half8 __attribute__((ext_vector_type(8)));
typedef _Float16 half4 __attribute__((ext_vector_type(4)));
typedef float    f32x4 __attribute__((ext_vector_type(4)));

__device__ __forceinline__ void gload_lds16(const void* g, void* l) {
    __builtin_amdgcn_global_load_lds(
        (const __attribute__((address_space(1))) void*)g,
        (__attribute__((address_space(3))) void*)l, 16, 0, 0);
}

// ---------------- x NCHW f32 -> xt NHWC f16 ----------------
__global__ __launch_bounds__(256) void k_transpose_x(const float* __restrict__ x,
                                                     _Float16* __restrict__ xt) {
    __shared__ float tile[32][33];
    int b  = blockIdx.z;
    int c0 = blockIdx.y * 32;
    int p0 = blockIdx.x * 32;
    int tx = threadIdx.x;   // 0..31
    int ty = threadIdx.y;   // 0..7
    const float* xb = x + (size_t)b * CH * HW;
    #pragma unroll
    for (int i = 0; i < 32; i += 8)
        tile[ty + i][tx] = xb[(size_t)(c0 + ty + i) * HW + p0 + tx];
    __syncthreads();
    _Float16* xtb = xt + (size_t)b * HW * CH;
    #pragma unroll
    for (int i = 0; i < 32; i += 8)
        xtb[(size_t)(p0 + ty + i) * CH + c0 + tx] = (_Float16)tile[tx][ty + i];
}

// ---------------- dcn_w [o][c][tap] f32 -> wpack [chunk][o][WROW] f16 ----------------
__global__ __launch_bounds__(256) void k_pack_w(const float* __restrict__ w,
                                                _Float16* __restrict__ wp) {
    int idx = blockIdx.x * 256 + threadIdx.x;
    if (idx >= NCHUNK * CH * WROW) return;
    int kq  = idx % WROW;
    int o   = (idx / WROW) % CH;
    int q   = idx / (WROW * CH);
    int tap = q >> 3;
    int c   = (q & 7) * 32 + kq;
    float v = (kq < 32) ? w[((size_t)o * CH + c) * KK + tap] : 0.f;
    wp[idx] = (_Float16)v;
}

// ---------------- offset_w [18][256][9] f32 -> wop [72 chunk][32 oc][32 k] f16 ----------------
__global__ __launch_bounds__(256) void k_pack_ow(const float* __restrict__ ow,
                                                 _Float16* __restrict__ wop) {
    int idx = blockIdx.x * 256 + threadIdx.x;
    if (idx >= NCHUNK * 32 * 32) return;
    int kq = idx & 31;
    int oc = (idx >> 5) & 31;
    int q  = idx >> 10;
    int tap = q >> 3;
    int c   = (q & 7) * 32 + kq;
    float v = (oc < CO) ? ow[((size_t)oc * CH + c) * KK + tap] : 0.f;
    wop[idx] = (_Float16)v;
}

// ---------------- fused offset-conv + deform-gather + MFMA GEMM + BN/SiLU/residual ----------------
// block: 256 threads = 4 waves; 32 px x 256 oc; wave wvi owns oc [64*wvi, 64*wvi+64)
__global__ __launch_bounds__(256) void k_main(const float* __restrict__ x,
                                              const _Float16* __restrict__ xt,
                                              const _Float16* __restrict__ wp,
                                              const _Float16* __restrict__ wop,
                                              const float* __restrict__ obias,
                                              const float* __restrict__ gamma,
                                              const float* __restrict__ beta,
                                              const float* __restrict__ mean,
                                              const float* __restrict__ var,
                                              float* __restrict__ out) {
    __shared__ int      cbase[PXB][KK][4];     // 4608 B
    __shared__ float    cwt[PXB][KK][4];       // 4608 B
    __shared__ _Float16 Bl[CH * WROW];         // 20480 B (weights tile, row stride 40)
    __shared__ _Float16 Al[PXB * WROW];        // 2560 B  (vals tile,   row stride 40)
    __shared__ float    offl[PXB][CO];         // 2304 B

    int t = threadIdx.x;
    int pixbase = blockIdx.x * PXB;
    int bb  = pixbase / HW;
    int hw0 = pixbase % HW;

    int lane = t & 63, wvi = t >> 6;
    int lm  = lane & 15;
    int kg8 = (lane >> 4) * 8;

    const _Float16* xtb = xt + (size_t)bb * HW * CH;

    // ---- phase 1: offset conv via MFMA ----
    // wave wvi: px-half pxf = wvi&1 (16 px), oc-frag ocf = wvi>>1 (oc 16*ocf..+16)
    {
        int pxf = wvi & 1, ocf = wvi >> 1;
        f32x4 oacc = (f32x4)0.f;
        int apx = (pixbase + pxf * 16 + lm) % HW;
        int h = apx / WW, w = apx % WW;
        #pragma unroll
        for (int tap = 0; tap < KK; ++tap) {
            int ki = tap / 3, kj = tap % 3;
            int yy = h + ki - 1, xx = w + kj - 1;
            bool ok = (yy >= 0) && (yy < HH) && (xx >= 0) && (xx < WW);
            const _Float16* asrc = xtb + (size_t)(yy * WW + xx) * CH + kg8;
            const _Float16* bsrc = wop + (size_t)(tap * 8 * 32 + ocf * 16 + lm) * 32 + kg8;
            #pragma unroll
            for (int cg = 0; cg < 8; ++cg) {
                half8 a = {0, 0, 0, 0, 0, 0, 0, 0};
                if (ok) a = *(const half8*)(asrc + cg * 32);
                half8 b = *(const half8*)(bsrc + cg * 1024);
                oacc = __builtin_amdgcn_mfma_f32_16x16x32_f16(a, b, oacc, 0, 0, 0);
            }
        }
        int prow = pxf * 16 + (lane >> 4) * 4;
        int oc = ocf * 16 + lm;
        if (oc < CO) {
            float bias = obias[oc];
            #pragma unroll
            for (int r = 0; r < 4; ++r) offl[prow + r][oc] = oacc[r] + bias;
        }
    }
    __syncthreads();

    // ---- phase 2: precompute bilinear corners/weights: 32 px x 9 taps ----
    for (int task = t; task < PXB * KK; task += 256) {
        int p = task / KK, tap = task % KK;
        int pix = pixbase + p;
        int hw = pix % HW;
        int hc = hw / WW, wc = hw % WW;
        float dy = offl[p][2 * tap];
        float dx = offl[p][2 * tap + 1];
        int ki = tap / 3, kj = tap % 3;
        float py = dy + (float)(hc - 1 + ki);
        float px = dx + (float)(wc - 1 + kj);
        float y0f = floorf(py), x0f = floorf(px);
        float wy = py - y0f, wx = px - x0f;
        int y0 = (int)y0f, x0 = (int)x0f;
        #pragma unroll
        for (int cy = 0; cy < 2; ++cy)
            #pragma unroll
            for (int cx = 0; cx < 2; ++cx) {
                int yy = y0 + cy, xx = x0 + cx;
                bool okc = (yy >= 0) && (yy < HH) && (xx >= 0) && (xx < WW);
                int yc = min(max(yy, 0), HH - 1);
                int xc = min(max(xx, 0), WW - 1);
                float wgt = (cy ? wy : 1.f - wy) * (cx ? wx : 1.f - wx);
                cbase[p][tap][cy * 2 + cx] = (yc * WW + xc) * CH;
                cwt[p][tap][cy * 2 + cx]   = okc ? wgt : 0.f;
            }
    }

    f32x4 acc[2][4];
    #pragma unroll
    for (int mm = 0; mm < 2; ++mm)
        #pragma unroll
        for (int nn = 0; nn < 4; ++nn) acc[mm][nn] = (f32x4)0.f;

    int gp = t >> 3, gq = t & 7;   // gather role: pixel gp, 4-ch quad gq

    for (int q = 0; q < NCHUNK; ++q) {
        int tap = q >> 3, cg = q & 7;
        __syncthreads();                   // previous chunk fully consumed
        // stage B async: 20480 B = 20 slices of 1024 B; wave wvi issues 5
        {
            const char* gB = (const char*)(wp + (size_t)q * CH * WROW);
            char* lB = (char*)Bl;
            #pragma unroll
            for (int i = 0; i < 5; ++i) {
                int sl = (wvi * 5 + i) * 1024;
                gload_lds16(gB + sl + lane * 16, lB + sl);
            }
        }
        // gather A: vals[gp][cg*32 + gq*4 .. +4], packed-f16 4-corner blend
        {
            const int*   cb = &cbase[gp][tap][0];
            const float* cw = &cwt[gp][tap][0];
            half4 vv = {0, 0, 0, 0};
            #pragma unroll
            for (int cn = 0; cn < 4; ++cn) {
                const _Float16* src = xtb + cb[cn] + cg * 32 + gq * 4;
                half4 a = *(const half4*)src;
                vv += a * (_Float16)cw[cn];
            }
            *(half4*)&Al[gp * WROW + gq * 4] = vv;
        }
        __syncthreads();
        // MFMA: 2 px-frags x 4 oc-frags per wave
        half8 af[2], bf[4];
        af[0] = *(const half8*)&Al[lm * WROW + kg8];
        af[1] = *(const half8*)&Al[(16 + lm) * WROW + kg8];
        #pragma unroll
        for (int nn = 0; nn < 4; ++nn)
            bf[nn] = *(const half8*)&Bl[(wvi * 64 + nn * 16 + lm) * WROW + kg8];
        #pragma unroll
        for (int mm = 0; mm < 2; ++mm)
            #pragma unroll
            for (int nn = 0; nn < 4; ++nn)
                acc[mm][nn] = __builtin_amdgcn_mfma_f32_16x16x32_f16(af[mm], bf[nn], acc[mm][nn], 0, 0, 0);
    }

    // --- epilogue: BN + SiLU + residual ---
    const float* xb2  = x   + (size_t)bb * CH * HW;
    float*       outb = out + (size_t)bb * CH * HW;
    #pragma unroll
    for (int nn = 0; nn < 4; ++nn) {
        int oc = wvi * 64 + nn * 16 + lm;
        float sc = gamma[oc] * rsqrtf(var[oc] + 1e-5f);
        float mn = mean[oc], bt = beta[oc];
        const float* xr   = xb2  + (size_t)oc * HW + hw0;
        float*       orow = outb + (size_t)oc * HW + hw0;
        #pragma unroll
        for (int mm = 0; mm < 2; ++mm) {
            #pragma unroll
            for (int r = 0; r < 4; ++r) {
                int px = mm * 16 + (lane >> 4) * 4 + r;
                float yv = (acc[mm][nn][r] - mn) * sc + bt;
                float s  = yv * __builtin_amdgcn_rcpf(1.f + __expf(-yv));
                orow[px] = xr[px] + s;
            }
        }
    }
}

extern "C" void kernel_launch(void* const* d_in, const int* in_sizes, int n_in,
                              void* d_out, int out_size, void* d_ws, size_t ws_size,
                              hipStream_t stream) {
    const float* x        = (const float*)d_in[0];
    const float* offset_w = (const float*)d_in[1];
    const float* offset_b = (const float*)d_in[2];
    const float* dcn_w    = (const float*)d_in[3];
    const float* gamma    = (const float*)d_in[4];
    const float* beta     = (const float*)d_in[5];
    const float* mean     = (const float*)d_in[6];
    const float* var      = (const float*)d_in[7];
    float* out = (float*)d_out;

    _Float16* xt  = (_Float16*)d_ws;                     // NPIX*CH f16   = 13,107,200 B
    _Float16* wpk = xt  + (size_t)NPIX * CH;             // 72*256*40 f16 =  1,474,560 B
    _Float16* wop = wpk + (size_t)NCHUNK * CH * WROW;    // 72*32*32 f16  =    147,456 B

    k_transpose_x<<<dim3(HW / 32, CH / 32, BATCH), dim3(32, 8), 0, stream>>>(x, xt);
    k_pack_w<<<(NCHUNK * CH * WROW + 255) / 256, 256, 0, stream>>>(dcn_w, wpk);
    k_pack_ow<<<(NCHUNK * 32 * 32 + 255) / 256, 256, 0, stream>>>(offset_w, wop);
    k_main<<<NBLK, 256, 0, stream>>>(x, xt, wpk, wop, offset_b,
                                     gamma, beta, mean, var, out);
}

// Round 5
// 139.710 us; speedup vs baseline: 1.2430x; 1.2430x over previous
//
#include <hip/hip_runtime.h>
#include <math.h>
#include <stdint.h>

#define BATCH 4
#define CH    256
#define HH    80
#define WW    80
#define HW    (HH*WW)        // 6400
#define NPIX  (BATCH*HW)     // 25600
#define KK    9
#define CO    18             // 2*K*K offset channels
#define NCHUNK 72            // 9 taps * 8 groups of 32 channels
#define WROW  40             // padded K-stride (elements) for LDS tiles (80 B)
#define PXB   64             // pixels per block
#define NBLK  (NPIX/PXB)     // 400 blocks

typedef _Float16 half8 __attribute__((ext_vector_type(8)));
typedef _Float16 half4 __attribute__((ext_vector_type(4)));
typedef float    f32x4 __attribute__((ext_vector_type(4)));

__device__ __forceinline__ void gload_lds16(const void* g, void* l) {
    __builtin_amdgcn_global_load_lds(
        (const __attribute__((address_space(1))) void*)g,
        (__attribute__((address_space(3))) void*)l, 16, 0, 0);
}

// ---------------- x NCHW f32 -> xt NHWC f16 ----------------
__global__ __launch_bounds__(256) void k_transpose_x(const float* __restrict__ x,
                                                     _Float16* __restrict__ xt) {
    __shared__ float tile[32][33];
    int b  = blockIdx.z;
    int c0 = blockIdx.y * 32;
    int p0 = blockIdx.x * 32;
    int tx = threadIdx.x;   // 0..31
    int ty = threadIdx.y;   // 0..7
    const float* xb = x + (size_t)b * CH * HW;
    #pragma unroll
    for (int i = 0; i < 32; i += 8)
        tile[ty + i][tx] = xb[(size_t)(c0 + ty + i) * HW + p0 + tx];
    __syncthreads();
    _Float16* xtb = xt + (size_t)b * HW * CH;
    #pragma unroll
    for (int i = 0; i < 32; i += 8)
        xtb[(size_t)(p0 + ty + i) * CH + c0 + tx] = (_Float16)tile[tx][ty + i];
}

// ---------------- dcn_w [o][c][tap] f32 -> wpack [chunk][o][WROW] f16 ----------------
__global__ __launch_bounds__(256) void k_pack_w(const float* __restrict__ w,
                                                _Float16* __restrict__ wp) {
    int idx = blockIdx.x * 256 + threadIdx.x;
    if (idx >= NCHUNK * CH * WROW) return;
    int kq  = idx % WROW;
    int o   = (idx / WROW) % CH;
    int q   = idx / (WROW * CH);
    int tap = q >> 3;
    int c   = (q & 7) * 32 + kq;
    float v = (kq < 32) ? w[((size_t)o * CH + c) * KK + tap] : 0.f;
    wp[idx] = (_Float16)v;
}

// ---------------- offset_w [18][256][9] f32 -> wop [72 chunk][32 oc][32 k] f16 ----------------
__global__ __launch_bounds__(256) void k_pack_ow(const float* __restrict__ ow,
                                                 _Float16* __restrict__ wop) {
    int idx = blockIdx.x * 256 + threadIdx.x;
    if (idx >= NCHUNK * 32 * 32) return;
    int kq = idx & 31;
    int oc = (idx >> 5) & 31;
    int q  = idx >> 10;
    int tap = q >> 3;
    int c   = (q & 7) * 32 + kq;
    float v = (oc < CO) ? ow[((size_t)oc * CH + c) * KK + tap] : 0.f;
    wop[idx] = (_Float16)v;
}

// ---------------- fused offset-conv + deform-gather + MFMA GEMM + BN/SiLU/residual ----------------
// block: 512 threads = 8 waves; 64 px x 256 oc; wave wvi owns oc [32*wvi, 32*wvi+32)
__global__ __launch_bounds__(512) void k_main(const float* __restrict__ x,
                                              const _Float16* __restrict__ xt,
                                              const _Float16* __restrict__ wp,
                                              const _Float16* __restrict__ wop,
                                              const float* __restrict__ obias,
                                              const float* __restrict__ gamma,
                                              const float* __restrict__ beta,
                                              const float* __restrict__ mean,
                                              const float* __restrict__ var,
                                              float* __restrict__ out) {
    __shared__ int      cbase[PXB][KK][4];     // 9216 B
    __shared__ float    cwt[PXB][KK][4];       // 9216 B
    __shared__ _Float16 Bl[2][CH * WROW];      // 40960 B (weights dbuf, row stride 40)
    __shared__ _Float16 Al[2][PXB * WROW];     // 10240 B (vals dbuf)
    __shared__ float    offl[PXB][CO];         // 4608 B
    // total 74240 B -> 2 blocks/CU

    int t = threadIdx.x;
    // bijective XCD swizzle: 400 % 8 == 0
    int tile = ((int)blockIdx.x & 7) * (NBLK / 8) + ((int)blockIdx.x >> 3);
    int pixbase = tile * PXB;
    int bb  = pixbase / HW;
    int hw0 = pixbase % HW;

    int lane = t & 63, wvi = t >> 6;           // 8 waves
    int lm  = lane & 15;
    int kg8 = (lane >> 4) * 8;

    const _Float16* xtb = xt + (size_t)bb * HW * CH;

    // ---- phase 1: offset conv via MFMA ----
    // wave wvi: px-frag pxf = wvi>>1 (16 px each), oc-frag ocf = wvi&1
    {
        int pxf = wvi >> 1, ocf = wvi & 1;
        f32x4 oacc = (f32x4)0.f;
        int apx = (pixbase + pxf * 16 + lm) % HW;
        int h = apx / WW, w = apx % WW;
        #pragma unroll
        for (int tap = 0; tap < KK; ++tap) {
            int ki = tap / 3, kj = tap % 3;
            int yy = h + ki - 1, xx = w + kj - 1;
            bool ok = (yy >= 0) && (yy < HH) && (xx >= 0) && (xx < WW);
            const _Float16* asrc = xtb + (size_t)(yy * WW + xx) * CH + kg8;
            const _Float16* bsrc = wop + (size_t)(tap * 8 * 32 + ocf * 16 + lm) * 32 + kg8;
            #pragma unroll
            for (int cg = 0; cg < 8; ++cg) {
                half8 a = {0, 0, 0, 0, 0, 0, 0, 0};
                if (ok) a = *(const half8*)(asrc + cg * 32);
                half8 b = *(const half8*)(bsrc + cg * 1024);
                oacc = __builtin_amdgcn_mfma_f32_16x16x32_f16(a, b, oacc, 0, 0, 0);
            }
        }
        int prow = pxf * 16 + (lane >> 4) * 4;
        int oc = ocf * 16 + lm;
        if (oc < CO) {
            float bias = obias[oc];
            #pragma unroll
            for (int r = 0; r < 4; ++r) offl[prow + r][oc] = oacc[r] + bias;
        }
    }
    __syncthreads();

    // ---- phase 2: bilinear corners/weights: 64 px x 9 taps ----
    for (int task = t; task < PXB * KK; task += 512) {
        int p = task / KK, tap = task % KK;
        int pix = pixbase + p;
        int hw = pix % HW;
        int hc = hw / WW, wc = hw % WW;
        float dy = offl[p][2 * tap];
        float dx = offl[p][2 * tap + 1];
        int ki = tap / 3, kj = tap % 3;
        float py = dy + (float)(hc - 1 + ki);
        float px = dx + (float)(wc - 1 + kj);
        float y0f = floorf(py), x0f = floorf(px);
        float wy = py - y0f, wx = px - x0f;
        int y0 = (int)y0f, x0 = (int)x0f;
        #pragma unroll
        for (int cy = 0; cy < 2; ++cy)
            #pragma unroll
            for (int cx = 0; cx < 2; ++cx) {
                int yy = y0 + cy, xx = x0 + cx;
                bool okc = (yy >= 0) && (yy < HH) && (xx >= 0) && (xx < WW);
                int yc = min(max(yy, 0), HH - 1);
                int xc = min(max(xx, 0), WW - 1);
                float wgt = (cy ? wy : 1.f - wy) * (cx ? wx : 1.f - wx);
                cbase[p][tap][cy * 2 + cx] = (yc * WW + xc) * CH;
                cwt[p][tap][cy * 2 + cx]   = okc ? wgt : 0.f;
            }
    }
    __syncthreads();

    f32x4 acc[4][2];
    #pragma unroll
    for (int mm = 0; mm < 4; ++mm)
        #pragma unroll
        for (int nn = 0; nn < 2; ++nn) acc[mm][nn] = (f32x4)0.f;

    int gp = t >> 3, q8 = t & 7;   // gather role: pixel gp, channel quad q8*4

    // ---- prologue: stage chunk 0 into buffer 0 ----
    {
        const char* gB = (const char*)(wp + 0);
        #pragma unroll
        for (int i = 0; i < 3; ++i) {
            int sl = wvi + 8 * i;
            if (sl < 20) gload_lds16(gB + sl * 1024 + lane * 16, ((char*)Bl[0]) + sl * 1024);
        }
        const int*   cb = &cbase[gp][0][0];
        const float* cw = &cwt[gp][0][0];
        half4 vv = {0, 0, 0, 0};
        #pragma unroll
        for (int cn = 0; cn < 4; ++cn) {
            const _Float16* src = xtb + cb[cn] + q8 * 4;
            half4 a = *(const half4*)src;
            vv += a * (_Float16)cw[cn];
        }
        *(half4*)&Al[0][gp * WROW + q8 * 4] = vv;
    }

    // ---- main loop: single barrier per chunk, dbuf pipeline ----
    for (int q = 0; q < NCHUNK; ++q) {
        int buf = q & 1;
        __syncthreads();   // stage(q) complete (lgkm + vmcnt drained by compiler)

        half4 pre[4];
        float pw[4];
        if (q < NCHUNK - 1) {
            int qn = q + 1;
            int ntap = qn >> 3, ncg = qn & 7;
            // issue next B stage (async -> LDS, other buffer)
            const char* gB = (const char*)(wp + (size_t)qn * CH * WROW);
            char* lB = (char*)Bl[buf ^ 1];
            #pragma unroll
            for (int i = 0; i < 3; ++i) {
                int sl = wvi + 8 * i;
                if (sl < 20) gload_lds16(gB + sl * 1024 + lane * 16, lB + sl * 1024);
            }
            // issue next A corner loads (global -> regs)
            const int*   cb = &cbase[gp][ntap][0];
            const float* cw = &cwt[gp][ntap][0];
            #pragma unroll
            for (int cn = 0; cn < 4; ++cn) {
                pre[cn] = *(const half4*)(xtb + cb[cn] + ncg * 32 + q8 * 4);
                pw[cn]  = cw[cn];
            }
        }

        // compute chunk q
        half8 af[4], bf[2];
        #pragma unroll
        for (int mm = 0; mm < 4; ++mm)
            af[mm] = *(const half8*)&Al[buf][(mm * 16 + lm) * WROW + kg8];
        #pragma unroll
        for (int nn = 0; nn < 2; ++nn)
            bf[nn] = *(const half8*)&Bl[buf][(wvi * 32 + nn * 16 + lm) * WROW + kg8];
        #pragma unroll
        for (int mm = 0; mm < 4; ++mm)
            #pragma unroll
            for (int nn = 0; nn < 2; ++nn)
                acc[mm][nn] = __builtin_amdgcn_mfma_f32_16x16x32_f16(af[mm], bf[nn], acc[mm][nn], 0, 0, 0);

        // blend + write next A (write-late)
        if (q < NCHUNK - 1) {
            half4 vv = {0, 0, 0, 0};
            #pragma unroll
            for (int cn = 0; cn < 4; ++cn) vv += pre[cn] * (_Float16)pw[cn];
            *(half4*)&Al[buf ^ 1][gp * WROW + q8 * 4] = vv;
        }
    }

    // --- epilogue: BN + SiLU + residual ---
    const float* xb2  = x   + (size_t)bb * CH * HW;
    float*       outb = out + (size_t)bb * CH * HW;
    #pragma unroll
    for (int nn = 0; nn < 2; ++nn) {
        int oc = wvi * 32 + nn * 16 + lm;
        float sc = gamma[oc] * rsqrtf(var[oc] + 1e-5f);
        float mn = mean[oc], bt = beta[oc];
        const float* xr   = xb2  + (size_t)oc * HW + hw0;
        float*       orow = outb + (size_t)oc * HW + hw0;
        #pragma unroll
        for (int mm = 0; mm < 4; ++mm) {
            #pragma unroll
            for (int r = 0; r < 4; ++r) {
                int px = mm * 16 + (lane >> 4) * 4 + r;
                float yv = (acc[mm][nn][r] - mn) * sc + bt;
                float s  = yv * __builtin_amdgcn_rcpf(1.f + __expf(-yv));
                orow[px] = xr[px] + s;
            }
        }
    }
}

extern "C" void kernel_launch(void* const* d_in, const int* in_sizes, int n_in,
                              void* d_out, int out_size, void* d_ws, size_t ws_size,
                              hipStream_t stream) {
    const float* x        = (const float*)d_in[0];
    const float* offset_w = (const float*)d_in[1];
    const float* offset_b = (const float*)d_in[2];
    const float* dcn_w    = (const float*)d_in[3];
    const float* gamma    = (const float*)d_in[4];
    const float* beta     = (const float*)d_in[5];
    const float* mean     = (const float*)d_in[6];
    const float* var      = (const float*)d_in[7];
    float* out = (float*)d_out;

    _Float16* xt  = (_Float16*)d_ws;                     // NPIX*CH f16   = 13,107,200 B
    _Float16* wpk = xt  + (size_t)NPIX * CH;             // 72*256*40 f16 =  1,474,560 B
    _Float16* wop = wpk + (size_t)NCHUNK * CH * WROW;    // 72*32*32 f16  =    147,456 B

    k_transpose_x<<<dim3(HW / 32, CH / 32, BATCH), dim3(32, 8), 0, stream>>>(x, xt);
    k_pack_w<<<(NCHUNK * CH * WROW + 255) / 256, 256, 0, stream>>>(dcn_w, wpk);
    k_pack_ow<<<(NCHUNK * 32 * 32 + 255) / 256, 256, 0, stream>>>(offset_w, wop);
    k_main<<<NBLK, 512, 0, stream>>>(x, xt, wpk, wop, offset_b,
                                     gamma, beta, mean, var, out);
}